// Round 4
// baseline (1749.936 us; speedup 1.0000x reference)
//
#include <hip/hip_runtime.h>

// Problem constants (from reference)
constexpr int CB   = 128;   // batch
constexpr int CC   = 12;    // channels
constexpr int CL   = 2048;  // length
constexpr int CK   = 8;     // kernels per group
constexpr int CG   = 32;    // _G = G/2
constexpr int CNCP = 6;     // channels summed per group
constexpr int CND  = 8;     // dilations
constexpr int HALO = 512;   // max tap reach = 4*128
constexpr int BUF  = HALO + CL + HALO + 16; // padded LDS row (3088 floats)

// ---------------------------------------------------------------------------
// Transpose W [pair][g*8+k][9] -> Wt [pair][g][j*8+k] (block-uniform weight
// reads become wide scalar loads).
// ---------------------------------------------------------------------------
__global__ void transposeW(const float* __restrict__ W, float* __restrict__ Wt) {
    int t = blockIdx.x * blockDim.x + threadIdx.x;
    constexpr int total = CND * 2 * CG * CK * 9; // 36864
    if (t >= total) return;
    int j = t % 9; int r = t / 9;
    int k = r % CK; r /= CK;
    int g = r % CG; int pair = r / CG;
    Wt[(pair * CG + g) * 72 + j * 8 + k] =
        W[((pair * (CG * CK)) + g * CK + k) * 9 + j];
}

__device__ __forceinline__ float4 ld4(const float* p) { return *(const float4*)p; }

// Compile-time component picker: element I of the 20-float window held in
// five float4 registers. Fully resolved at compile time (no private arrays).
template <int I>
__device__ __forceinline__ float pick(float4 t0, float4 t1, float4 t2, float4 t3, float4 t4) {
    constexpr int q = I >> 2, r = I & 3;
    float4 t;
    if constexpr (q == 0) t = t0; else if constexpr (q == 1) t = t1;
    else if constexpr (q == 2) t = t2; else if constexpr (q == 3) t = t3;
    else t = t4;
    if constexpr (r == 0) return t.x; else if constexpr (r == 1) return t.y;
    else if constexpr (r == 2) return t.z; else return t.w;
}

// Tournament max/argmax + argmin over 8 scalars; strict compares keep first
// occurrence on ties (matches jnp.argmax/argmin). Then LDS histogram update.
__device__ __forceinline__ void sel8_hist(float v0, float v1, float v2, float v3,
                                          float v4, float v5, float v6, float v7,
                                          float* hist, bool valid) {
    float a0 = v0, a1 = v2, a2 = v4, a3 = v6; int i0 = 0, i1 = 2, i2 = 4, i3 = 6;
    if (v1 > a0) { a0 = v1; i0 = 1; }
    if (v3 > a1) { a1 = v3; i1 = 3; }
    if (v5 > a2) { a2 = v5; i2 = 5; }
    if (v7 > a3) { a3 = v7; i3 = 7; }
    if (a1 > a0) { a0 = a1; i0 = i1; }
    if (a3 > a2) { a2 = a3; i2 = i3; }
    if (a2 > a0) { a0 = a2; i0 = i2; }
    float b0 = v0, b1 = v2, b2 = v4, b3 = v6; int j0 = 0, j1 = 2, j2 = 4, j3 = 6;
    if (v1 < b0) { b0 = v1; j0 = 1; }
    if (v3 < b1) { b1 = v3; j1 = 3; }
    if (v5 < b2) { b2 = v5; j2 = 5; }
    if (v7 < b3) { b3 = v7; j3 = 7; }
    if (b1 < b0) { b0 = b1; j0 = j1; }
    if (b3 < b2) { b2 = b3; j0 = j0, j2 = j3; }
    if (b3 < b2) { b2 = b3; j2 = j3; }
    if (b2 < b0) { b0 = b2; j0 = j2; }
    if (valid) {
        unsafeAtomicAdd(&hist[i0], a0);
        unsafeAtomicAdd(&hist[8 + j0], 1.0f);
    }
}

// 8 FMAs of one tap float4 (tv) against weights wj[0..7] into float4 accs a0..a7
#define FK(K) { const float wk_ = wj[K]; \
    a##K.x = fmaf(wk_, tv.x, a##K.x); a##K.y = fmaf(wk_, tv.y, a##K.y); \
    a##K.z = fmaf(wk_, tv.z, a##K.z); a##K.w = fmaf(wk_, tv.w, a##K.w); }
#define FK8 FK(0) FK(1) FK(2) FK(3) FK(4) FK(5) FK(6) FK(7)
#define FOR9(M) M(0) M(1) M(2) M(3) M(4) M(5) M(6) M(7) M(8)

// Conv for runtime D in {4..128} (D%4==0 -> aligned float4 taps).
__device__ __forceinline__ void conv_big(const float* inp, const float* __restrict__ Wg,
                                         float* hist, int D, int Lout, int tid) {
    #pragma unroll
    for (int pass = 0; pass < 2; ++pass) {
        const int l0 = pass * 1024 + tid * 4;
        const float* base = inp + HALO + l0;
        float4 a0 = make_float4(0, 0, 0, 0), a1 = a0, a2 = a0, a3 = a0,
               a4 = a0, a5 = a0, a6 = a0, a7 = a0;
        #pragma unroll
        for (int j = 0; j < 9; ++j) {
            const float4 tv = ld4(base + (j - 4) * D);
            const float* wj = Wg + j * 8;
            FK8
        }
        sel8_hist(a0.x, a1.x, a2.x, a3.x, a4.x, a5.x, a6.x, a7.x, hist, (l0 + 0) < Lout);
        sel8_hist(a0.y, a1.y, a2.y, a3.y, a4.y, a5.y, a6.y, a7.y, hist, (l0 + 1) < Lout);
        sel8_hist(a0.z, a1.z, a2.z, a3.z, a4.z, a5.z, a6.z, a7.z, hist, (l0 + 2) < Lout);
        sel8_hist(a0.w, a1.w, a2.w, a3.w, a4.w, a5.w, a6.w, a7.w, hist, (l0 + 3) < Lout);
    }
}

// Conv for D = 1 or 2: sliding window in 3 or 5 float4 registers.
template <int DD>
__device__ __forceinline__ void conv_small(const float* inp, const float* __restrict__ Wg,
                                           float* hist, int Lout, int tid) {
    #pragma unroll
    for (int pass = 0; pass < 2; ++pass) {
        const int l0 = pass * 1024 + tid * 4;
        const float* base = inp + HALO + l0 - 4 * DD; // 16B aligned
        const float4 t0 = ld4(base), t1 = ld4(base + 4), t2 = ld4(base + 8);
        float4 t3, t4;
        if constexpr (DD == 2) { t3 = ld4(base + 12); t4 = ld4(base + 16); }
        else { t3 = t2; t4 = t2; }
        float4 a0 = make_float4(0, 0, 0, 0), a1 = a0, a2 = a0, a3 = a0,
               a4 = a0, a5 = a0, a6 = a0, a7 = a0;
        // tap(p, j) = window[p + j*DD]
        #define TAP(J) { \
            const float4 tv = make_float4(pick<(J) * DD + 0>(t0, t1, t2, t3, t4), \
                                          pick<(J) * DD + 1>(t0, t1, t2, t3, t4), \
                                          pick<(J) * DD + 2>(t0, t1, t2, t3, t4), \
                                          pick<(J) * DD + 3>(t0, t1, t2, t3, t4)); \
            const float* wj = Wg + (J) * 8; FK8 }
        FOR9(TAP)
        #undef TAP
        sel8_hist(a0.x, a1.x, a2.x, a3.x, a4.x, a5.x, a6.x, a7.x, hist, (l0 + 0) < Lout);
        sel8_hist(a0.y, a1.y, a2.y, a3.y, a4.y, a5.y, a6.y, a7.y, hist, (l0 + 1) < Lout);
        sel8_hist(a0.z, a1.z, a2.z, a3.z, a4.z, a5.z, a6.z, a7.z, hist, (l0 + 2) < Lout);
        sel8_hist(a0.w, a1.w, a2.w, a3.w, a4.w, a5.w, a6.w, a7.w, hist, (l0 + 3) < Lout);
    }
}

// ---------------------------------------------------------------------------
// ONE block per (b, pair); loops over all 32 groups internally. 2048 blocks
// total (was 65536): amortizes the measured ~64 cyc/WG fixed overhead 32x.
// ---------------------------------------------------------------------------
__global__ void __launch_bounds__(256)
hydra_fused(const float* __restrict__ X, const float* __restrict__ Wt,
            const int* __restrict__ I, float* __restrict__ out)
{
    __shared__ float inp[BUF];
    __shared__ float hist[16];
    const int tid  = threadIdx.x;
    const int blk  = blockIdx.x;
    const int pair = blk & 15;
    const int b    = blk >> 4;
    const int di   = pair >> 1;
    const int diffi = pair & 1;
    const int D    = 1 << di;
    const int Lout = CL - diffi;
    const float* __restrict__ Xb = X + (size_t)b * (CC * CL);

    for (int i = tid; i < HALO; i += 256) inp[i] = 0.f;
    for (int i = HALO + CL + tid; i < BUF; i += 256) inp[i] = 0.f;
    if (tid < 16) hist[tid] = 0.f;

    for (int g = 0; g < CG; ++g) {
        // ---- stage summed (and optionally diffed) row for this group ----
        const int* __restrict__ Ig = I + (pair * CG + g) * CNCP;
        const int c0 = Ig[0], c1 = Ig[1], c2 = Ig[2],
                  c3 = Ig[3], c4 = Ig[4], c5 = Ig[5];
        const float* r0 = Xb + c0 * CL; const float* r1 = Xb + c1 * CL;
        const float* r2 = Xb + c2 * CL; const float* r3 = Xb + c3 * CL;
        const float* r4 = Xb + c4 * CL; const float* r5 = Xb + c5 * CL;

        #pragma unroll
        for (int cc = 0; cc < 2; ++cc) {
            const int pos = cc * 1024 + tid * 4;
            const float4 x0 = ld4(r0 + pos), x1 = ld4(r1 + pos), x2 = ld4(r2 + pos),
                         x3 = ld4(r3 + pos), x4 = ld4(r4 + pos), x5 = ld4(r5 + pos);
            float4 s;
            s.x = ((x0.x + x1.x) + (x2.x + x3.x)) + (x4.x + x5.x);
            s.y = ((x0.y + x1.y) + (x2.y + x3.y)) + (x4.y + x5.y);
            s.z = ((x0.z + x1.z) + (x2.z + x3.z)) + (x4.z + x5.z);
            s.w = ((x0.w + x1.w) + (x2.w + x3.w)) + (x4.w + x5.w);
            if (!diffi) {
                *(float4*)&inp[HALO + pos] = s;
            } else {
                // diff fused into staging: d[l] = S[l+1]-S[l]; final element 0.
                float s4;
                if (pos + 4 < CL)
                    s4 = ((r0[pos + 4] + r1[pos + 4]) + (r2[pos + 4] + r3[pos + 4]))
                         + (r4[pos + 4] + r5[pos + 4]);
                else
                    s4 = s.w; // => diff 0 at padding position 2047
                const float4 d = make_float4(s.y - s.x, s.z - s.y, s.w - s.z, s4 - s.w);
                *(float4*)&inp[HALO + pos] = d;
            }
        }
        __syncthreads();

        // ---- conv + select + histogram ----
        const float* __restrict__ Wg = Wt + (pair * CG + g) * 72;
        if (di >= 2)      conv_big(inp, Wg, hist, D, Lout, tid);
        else if (di == 1) conv_small<2>(inp, Wg, hist, Lout, tid);
        else              conv_small<1>(inp, Wg, hist, Lout, tid);
        __syncthreads();

        // ---- epilogue for this group; reset hist for the next ----
        if (tid < 16) {
            const int which = tid >> 3, k = tid & 7;
            out[(size_t)b * 8192 + ((pair * 2 + which) * CG + g) * CK + k] = hist[tid];
            hist[tid] = 0.f;
        }
    }
}

extern "C" void kernel_launch(void* const* d_in, const int* in_sizes, int n_in,
                              void* d_out, int out_size, void* d_ws, size_t ws_size,
                              hipStream_t stream)
{
    const float* X = (const float*)d_in[0];
    const float* W = (const float*)d_in[1];
    const int*   I = (const int*)d_in[2];
    float* out = (float*)d_out;
    float* Wt  = (float*)d_ws; // 36864 floats = 144 KiB scratch

    transposeW<<<dim3((36864 + 255) / 256), dim3(256), 0, stream>>>(W, Wt);
    hydra_fused<<<dim3(CB * 16), dim3(256), 0, stream>>>(X, Wt, I, out);
}

// Round 5
// 1607.184 us; speedup vs baseline: 1.0888x; 1.0888x over previous
//
#include <hip/hip_runtime.h>

// Problem constants (from reference)
constexpr int CB   = 128;   // batch
constexpr int CC   = 12;    // channels
constexpr int CL   = 2048;  // length
constexpr int CK   = 8;     // kernels per group
constexpr int CG   = 32;    // _G = G/2
constexpr int CNCP = 6;     // channels summed per group
constexpr int CND  = 8;     // dilations
constexpr int HALO = 512;   // max tap reach = 4*128
constexpr int BUF  = HALO + CL + HALO + 16; // padded LDS row (3088 floats)

// ---------------------------------------------------------------------------
// Transpose W [pair][g*8+k][9] -> Wt [pair][g][j*8+k] (block-uniform weight
// reads become wide scalar loads).
// ---------------------------------------------------------------------------
__global__ void transposeW(const float* __restrict__ W, float* __restrict__ Wt) {
    int t = blockIdx.x * blockDim.x + threadIdx.x;
    constexpr int total = CND * 2 * CG * CK * 9; // 36864
    if (t >= total) return;
    int j = t % 9; int r = t / 9;
    int k = r % CK; r /= CK;
    int g = r % CG; int pair = r / CG;
    Wt[(pair * CG + g) * 72 + j * 8 + k] =
        W[((pair * (CG * CK)) + g * CK + k) * 9 + j];
}

__device__ __forceinline__ float4 ld4(const float* p) { return *(const float4*)p; }

// Tournament max/argmax + argmin over 8 scalars; strict compares keep first
// occurrence on ties (matches jnp.argmax/argmin). Then LDS histogram update.
__device__ __forceinline__ void sel8_hist(float v0, float v1, float v2, float v3,
                                          float v4, float v5, float v6, float v7,
                                          float* hist, bool valid) {
    float a0 = v0, a1 = v2, a2 = v4, a3 = v6; int i0 = 0, i1 = 2, i2 = 4, i3 = 6;
    if (v1 > a0) { a0 = v1; i0 = 1; }
    if (v3 > a1) { a1 = v3; i1 = 3; }
    if (v5 > a2) { a2 = v5; i2 = 5; }
    if (v7 > a3) { a3 = v7; i3 = 7; }
    if (a1 > a0) { a0 = a1; i0 = i1; }
    if (a3 > a2) { a2 = a3; i2 = i3; }
    if (a2 > a0) { a0 = a2; i0 = i2; }
    float b0 = v0, b1 = v2, b2 = v4, b3 = v6; int j0 = 0, j1 = 2, j2 = 4, j3 = 6;
    if (v1 < b0) { b0 = v1; j0 = 1; }
    if (v3 < b1) { b1 = v3; j1 = 3; }
    if (v5 < b2) { b2 = v5; j2 = 5; }
    if (v7 < b3) { b3 = v7; j3 = 7; }
    if (b1 < b0) { b0 = b1; j0 = j1; }
    if (b3 < b2) { b2 = b3; j2 = j3; }
    if (b2 < b0) { b0 = b2; j0 = j2; }
    if (valid) {
        unsafeAtomicAdd(&hist[i0], a0);
        unsafeAtomicAdd(&hist[8 + j0], 1.0f);
    }
}

// ---------------------------------------------------------------------------
// ONE block per (b, pair); loops over 32 groups. Conv inner loop: ONE position
// per thread, 8 scalar accumulators -> ~20 live VGPRs, spill-proof.
// p-loop and g-loop deliberately NOT unrolled (keeps live ranges small).
// ---------------------------------------------------------------------------
__global__ void __launch_bounds__(256)
hydra_fused(const float* __restrict__ X, const float* __restrict__ Wt,
            const int* __restrict__ I, float* __restrict__ out)
{
    __shared__ float inp[BUF];
    __shared__ float hist[16];
    const int tid   = threadIdx.x;
    const int blk   = blockIdx.x;
    const int pair  = blk & 15;
    const int b     = blk >> 4;
    const int di    = pair >> 1;
    const int diffi = pair & 1;
    const int D     = 1 << di;
    const int Lout  = CL - diffi;
    const float* __restrict__ Xb = X + (size_t)b * (CC * CL);

    for (int i = tid; i < HALO; i += 256) inp[i] = 0.f;
    for (int i = HALO + CL + tid; i < BUF; i += 256) inp[i] = 0.f;
    if (tid < 16) hist[tid] = 0.f;

    #pragma unroll 1
    for (int g = 0; g < CG; ++g) {
        // ---- stage summed (and optionally diffed) row for this group ----
        const int* __restrict__ Ig = I + (pair * CG + g) * CNCP;
        const int c0 = Ig[0], c1 = Ig[1], c2 = Ig[2],
                  c3 = Ig[3], c4 = Ig[4], c5 = Ig[5];
        const float* r0 = Xb + c0 * CL; const float* r1 = Xb + c1 * CL;
        const float* r2 = Xb + c2 * CL; const float* r3 = Xb + c3 * CL;
        const float* r4 = Xb + c4 * CL; const float* r5 = Xb + c5 * CL;

        #pragma unroll
        for (int cc = 0; cc < 2; ++cc) {
            const int pos = cc * 1024 + tid * 4;
            const float4 x0 = ld4(r0 + pos), x1 = ld4(r1 + pos), x2 = ld4(r2 + pos),
                         x3 = ld4(r3 + pos), x4 = ld4(r4 + pos), x5 = ld4(r5 + pos);
            float4 s;
            s.x = ((x0.x + x1.x) + (x2.x + x3.x)) + (x4.x + x5.x);
            s.y = ((x0.y + x1.y) + (x2.y + x3.y)) + (x4.y + x5.y);
            s.z = ((x0.z + x1.z) + (x2.z + x3.z)) + (x4.z + x5.z);
            s.w = ((x0.w + x1.w) + (x2.w + x3.w)) + (x4.w + x5.w);
            if (!diffi) {
                *(float4*)&inp[HALO + pos] = s;
            } else {
                // diff fused into staging: d[l] = S[l+1]-S[l]; final element 0.
                float s4;
                if (pos + 4 < CL)
                    s4 = ((r0[pos + 4] + r1[pos + 4]) + (r2[pos + 4] + r3[pos + 4]))
                         + (r4[pos + 4] + r5[pos + 4]);
                else
                    s4 = s.w; // => diff 0 at padding position 2047
                const float4 d = make_float4(s.y - s.x, s.z - s.y, s.w - s.z, s4 - s.w);
                *(float4*)&inp[HALO + pos] = d;
            }
        }
        __syncthreads();

        // ---- conv + select + histogram: 1 position/thread, scalar accs ----
        const float* __restrict__ Wg = Wt + (pair * CG + g) * 72;
        #pragma unroll 1
        for (int p = 0; p < 8; ++p) {
            const int l = p * 256 + tid;               // lane-consecutive
            const float* base = &inp[HALO + l - 4 * D];
            float a0 = 0.f, a1 = 0.f, a2 = 0.f, a3 = 0.f,
                  a4 = 0.f, a5 = 0.f, a6 = 0.f, a7 = 0.f;
            #pragma unroll
            for (int j = 0; j < 9; ++j) {
                const float tv = base[j * D];
                const float* wj = Wg + j * 8;          // block-uniform -> SGPR
                a0 = fmaf(wj[0], tv, a0);
                a1 = fmaf(wj[1], tv, a1);
                a2 = fmaf(wj[2], tv, a2);
                a3 = fmaf(wj[3], tv, a3);
                a4 = fmaf(wj[4], tv, a4);
                a5 = fmaf(wj[5], tv, a5);
                a6 = fmaf(wj[6], tv, a6);
                a7 = fmaf(wj[7], tv, a7);
            }
            sel8_hist(a0, a1, a2, a3, a4, a5, a6, a7, hist, l < Lout);
        }
        __syncthreads();

        // ---- epilogue for this group; reset hist for the next ----
        if (tid < 16) {
            const int which = tid >> 3, k = tid & 7;
            out[(size_t)b * 8192 + ((pair * 2 + which) * CG + g) * CK + k] = hist[tid];
            hist[tid] = 0.f;
        }
    }
}

extern "C" void kernel_launch(void* const* d_in, const int* in_sizes, int n_in,
                              void* d_out, int out_size, void* d_ws, size_t ws_size,
                              hipStream_t stream)
{
    const float* X = (const float*)d_in[0];
    const float* W = (const float*)d_in[1];
    const int*   I = (const int*)d_in[2];
    float* out = (float*)d_out;
    float* Wt  = (float*)d_ws; // 36864 floats = 144 KiB scratch

    transposeW<<<dim3((36864 + 255) / 256), dim3(256), 0, stream>>>(W, Wt);
    hydra_fused<<<dim3(CB * 16), dim3(256), 0, stream>>>(X, Wt, I, out);
}

// Round 6
// 714.443 us; speedup vs baseline: 2.4494x; 2.2496x over previous
//
#include <hip/hip_runtime.h>

// Problem constants (from reference)
constexpr int CB   = 128;   // batch
constexpr int CC   = 12;    // channels
constexpr int CL   = 2048;  // length
constexpr int CK   = 8;     // kernels per group
constexpr int CG   = 32;    // _G = G/2
constexpr int CNCP = 6;     // channels summed per group
constexpr int CND  = 8;     // dilations
constexpr int HALO = 512;   // max tap reach = 4*128
constexpr int BUF  = HALO + CL + HALO + 16; // padded LDS row (3088 floats)

// ---------------------------------------------------------------------------
// Transpose W [pair][g*8+k][9] -> Wt [pair][g][j*8+k] (block-uniform weight
// reads become wide scalar loads).
// ---------------------------------------------------------------------------
__global__ void transposeW(const float* __restrict__ W, float* __restrict__ Wt) {
    int t = blockIdx.x * blockDim.x + threadIdx.x;
    constexpr int total = CND * 2 * CG * CK * 9; // 36864
    if (t >= total) return;
    int j = t % 9; int r = t / 9;
    int k = r % CK; r /= CK;
    int g = r % CG; int pair = r / CG;
    Wt[(pair * CG + g) * 72 + j * 8 + k] =
        W[((pair * (CG * CK)) + g * CK + k) * 9 + j];
}

__device__ __forceinline__ float4 ld4(const float* p) { return *(const float4*)p; }

// Butterfly sum over all 64 lanes (wave64).
#define RED64(v) { v += __shfl_xor(v, 32); v += __shfl_xor(v, 16); \
                   v += __shfl_xor(v, 8);  v += __shfl_xor(v, 4);  \
                   v += __shfl_xor(v, 2);  v += __shfl_xor(v, 1); }

// ---------------------------------------------------------------------------
// ONE block per (b, pair); loops over 32 groups. NO per-position LDS atomics:
// per-thread register bins (8 max-sums + 8 min-counts), per-g wave butterfly
// reduction, per-wave LDS slot, 16-thread final combine.
// ---------------------------------------------------------------------------
__global__ void __launch_bounds__(256)
hydra_fused(const float* __restrict__ X, const float* __restrict__ Wt,
            const int* __restrict__ I, float* __restrict__ out)
{
    __shared__ float inp[BUF];
    __shared__ float wavehist[4 * 16]; // [wave][bin]; bin<8 max-sum, bin>=8 min-count
    const int tid   = threadIdx.x;
    const int blk   = blockIdx.x;
    const int pair  = blk & 15;
    const int b     = blk >> 4;
    const int di    = pair >> 1;
    const int diffi = pair & 1;
    const int D     = 1 << di;
    const int Lout  = CL - diffi;
    const float* __restrict__ Xb = X + (size_t)b * (CC * CL);

    for (int i = tid; i < HALO; i += 256) inp[i] = 0.f;
    for (int i = HALO + CL + tid; i < BUF; i += 256) inp[i] = 0.f;

    #pragma unroll 1
    for (int g = 0; g < CG; ++g) {
        // ---- stage summed (and optionally diffed) row for this group ----
        const int* __restrict__ Ig = I + (pair * CG + g) * CNCP;
        const int c0 = Ig[0], c1 = Ig[1], c2 = Ig[2],
                  c3 = Ig[3], c4 = Ig[4], c5 = Ig[5];
        const float* r0 = Xb + c0 * CL; const float* r1 = Xb + c1 * CL;
        const float* r2 = Xb + c2 * CL; const float* r3 = Xb + c3 * CL;
        const float* r4 = Xb + c4 * CL; const float* r5 = Xb + c5 * CL;

        #pragma unroll
        for (int cc = 0; cc < 2; ++cc) {
            const int pos = cc * 1024 + tid * 4;
            const float4 x0 = ld4(r0 + pos), x1 = ld4(r1 + pos), x2 = ld4(r2 + pos),
                         x3 = ld4(r3 + pos), x4 = ld4(r4 + pos), x5 = ld4(r5 + pos);
            float4 s;
            s.x = ((x0.x + x1.x) + (x2.x + x3.x)) + (x4.x + x5.x);
            s.y = ((x0.y + x1.y) + (x2.y + x3.y)) + (x4.y + x5.y);
            s.z = ((x0.z + x1.z) + (x2.z + x3.z)) + (x4.z + x5.z);
            s.w = ((x0.w + x1.w) + (x2.w + x3.w)) + (x4.w + x5.w);
            if (!diffi) {
                *(float4*)&inp[HALO + pos] = s;
            } else {
                // diff fused into staging: d[l] = S[l+1]-S[l]; final element 0.
                float s4;
                if (pos + 4 < CL)
                    s4 = ((r0[pos + 4] + r1[pos + 4]) + (r2[pos + 4] + r3[pos + 4]))
                         + (r4[pos + 4] + r5[pos + 4]);
                else
                    s4 = s.w; // => diff 0 at padding position 2047
                const float4 d = make_float4(s.y - s.x, s.z - s.y, s.w - s.z, s4 - s.w);
                *(float4*)&inp[HALO + pos] = d;
            }
        }
        __syncthreads();

        // ---- conv + select + REGISTER bins (no atomics) ----
        const float* __restrict__ Wg = Wt + (pair * CG + g) * 72;
        float bm0 = 0.f, bm1 = 0.f, bm2 = 0.f, bm3 = 0.f,
              bm4 = 0.f, bm5 = 0.f, bm6 = 0.f, bm7 = 0.f;
        float bn0 = 0.f, bn1 = 0.f, bn2 = 0.f, bn3 = 0.f,
              bn4 = 0.f, bn5 = 0.f, bn6 = 0.f, bn7 = 0.f;

        #pragma unroll 1
        for (int p = 0; p < 8; ++p) {
            const int l = p * 256 + tid;               // lane-consecutive
            const float* base = &inp[HALO + l - 4 * D];
            float a0 = 0.f, a1 = 0.f, a2 = 0.f, a3 = 0.f,
                  a4 = 0.f, a5 = 0.f, a6 = 0.f, a7 = 0.f;
            #pragma unroll
            for (int j = 0; j < 9; ++j) {
                const float tv = base[j * D];
                const float* wj = Wg + j * 8;          // block-uniform -> SGPR
                a0 = fmaf(wj[0], tv, a0);
                a1 = fmaf(wj[1], tv, a1);
                a2 = fmaf(wj[2], tv, a2);
                a3 = fmaf(wj[3], tv, a3);
                a4 = fmaf(wj[4], tv, a4);
                a5 = fmaf(wj[5], tv, a5);
                a6 = fmaf(wj[6], tv, a6);
                a7 = fmaf(wj[7], tv, a7);
            }
            // tournament max/argmax + argmin; strict compares keep first index
            float mxv = a0, x1v = a2, x2v = a4, x3v = a6;
            int   mi = 0,  i1 = 2,  i2 = 4,  i3 = 6;
            if (a1 > mxv) { mxv = a1; mi = 1; }
            if (a3 > x1v) { x1v = a3; i1 = 3; }
            if (a5 > x2v) { x2v = a5; i2 = 5; }
            if (a7 > x3v) { x3v = a7; i3 = 7; }
            if (x1v > mxv) { mxv = x1v; mi = i1; }
            if (x3v > x2v) { x2v = x3v; i2 = i3; }
            if (x2v > mxv) { mxv = x2v; mi = i2; }
            float n0v = a0, n1v = a2, n2v = a4, n3v = a6;
            int   ni = 0,  j1 = 2,  j2 = 4,  j3 = 6;
            if (a1 < n0v) { n0v = a1; ni = 1; }
            if (a3 < n1v) { n1v = a3; j1 = 3; }
            if (a5 < n2v) { n2v = a5; j2 = 5; }
            if (a7 < n3v) { n3v = a7; j3 = 7; }
            if (n1v < n0v) { n0v = n1v; ni = j1; }
            if (n3v < n2v) { n2v = n3v; j2 = j3; }
            if (n2v < n0v) { n0v = n2v; ni = j2; }

            if (l >= Lout) { mi = -1; ni = -1; } // padding position: no bin
            bm0 += (mi == 0) ? mxv : 0.f;  bm1 += (mi == 1) ? mxv : 0.f;
            bm2 += (mi == 2) ? mxv : 0.f;  bm3 += (mi == 3) ? mxv : 0.f;
            bm4 += (mi == 4) ? mxv : 0.f;  bm5 += (mi == 5) ? mxv : 0.f;
            bm6 += (mi == 6) ? mxv : 0.f;  bm7 += (mi == 7) ? mxv : 0.f;
            bn0 += (ni == 0) ? 1.f : 0.f;  bn1 += (ni == 1) ? 1.f : 0.f;
            bn2 += (ni == 2) ? 1.f : 0.f;  bn3 += (ni == 3) ? 1.f : 0.f;
            bn4 += (ni == 4) ? 1.f : 0.f;  bn5 += (ni == 5) ? 1.f : 0.f;
            bn6 += (ni == 6) ? 1.f : 0.f;  bn7 += (ni == 7) ? 1.f : 0.f;
        }

        // ---- wave butterfly reduction of the 16 bins ----
        RED64(bm0) RED64(bm1) RED64(bm2) RED64(bm3)
        RED64(bm4) RED64(bm5) RED64(bm6) RED64(bm7)
        RED64(bn0) RED64(bn1) RED64(bn2) RED64(bn3)
        RED64(bn4) RED64(bn5) RED64(bn6) RED64(bn7)

        if ((tid & 63) == 0) {
            float* wh = wavehist + (tid >> 6) * 16;
            *(float4*)(wh + 0)  = make_float4(bm0, bm1, bm2, bm3);
            *(float4*)(wh + 4)  = make_float4(bm4, bm5, bm6, bm7);
            *(float4*)(wh + 8)  = make_float4(bn0, bn1, bn2, bn3);
            *(float4*)(wh + 12) = make_float4(bn4, bn5, bn6, bn7);
        }
        __syncthreads();

        // ---- combine 4 wave slots, write out; next stage may overwrite inp
        //      only after the next iteration's barrier ----
        if (tid < 16) {
            const float s = wavehist[tid] + wavehist[16 + tid]
                          + wavehist[32 + tid] + wavehist[48 + tid];
            const int which = tid >> 3, k = tid & 7;
            out[(size_t)b * 8192 + ((pair * 2 + which) * CG + g) * CK + k] = s;
        }
    }
}

extern "C" void kernel_launch(void* const* d_in, const int* in_sizes, int n_in,
                              void* d_out, int out_size, void* d_ws, size_t ws_size,
                              hipStream_t stream)
{
    const float* X = (const float*)d_in[0];
    const float* W = (const float*)d_in[1];
    const int*   I = (const int*)d_in[2];
    float* out = (float*)d_out;
    float* Wt  = (float*)d_ws; // 36864 floats = 144 KiB scratch

    transposeW<<<dim3((36864 + 255) / 256), dim3(256), 0, stream>>>(W, Wt);
    hydra_fused<<<dim3(CB * 16), dim3(256), 0, stream>>>(X, Wt, I, out);
}

// Round 8
// 642.743 us; speedup vs baseline: 2.7226x; 1.1116x over previous
//
#include <hip/hip_runtime.h>

typedef float v2f __attribute__((ext_vector_type(2)));

// Problem constants (from reference)
constexpr int CB   = 128;   // batch
constexpr int CC   = 12;    // channels
constexpr int CL   = 2048;  // length
constexpr int CK   = 8;     // kernels per group
constexpr int CG   = 32;    // _G = G/2
constexpr int CNCP = 6;     // channels summed per group
constexpr int CND  = 8;     // dilations
constexpr int HALO = 512;   // max tap reach = 4*128
constexpr int BUF  = HALO + CL + HALO + 16; // padded LDS row (3088 floats)

// ---------------------------------------------------------------------------
// Transpose W [pair][g*8+k][9] -> Wt [pair][g][j*8+k] (block-uniform weight
// reads become wide scalar loads).
// ---------------------------------------------------------------------------
__global__ void transposeW(const float* __restrict__ W, float* __restrict__ Wt) {
    int t = blockIdx.x * blockDim.x + threadIdx.x;
    constexpr int total = CND * 2 * CG * CK * 9; // 36864
    if (t >= total) return;
    int j = t % 9; int r = t / 9;
    int k = r % CK; r /= CK;
    int g = r % CG; int pair = r / CG;
    Wt[(pair * CG + g) * 72 + j * 8 + k] =
        W[((pair * (CG * CK)) + g * CK + k) * 9 + j];
}

__device__ __forceinline__ float4 ld4(const float* p) { return *(const float4*)p; }
__device__ __forceinline__ v2f vmax(v2f a, v2f b) { return __builtin_elementwise_max(a, b); }
__device__ __forceinline__ v2f vmin(v2f a, v2f b) { return __builtin_elementwise_min(a, b); }

// Butterfly sum over all 64 lanes (wave64).
#define RED64(v) { v += __shfl_xor(v, 32); v += __shfl_xor(v, 16); \
                   v += __shfl_xor(v, 8);  v += __shfl_xor(v, 4);  \
                   v += __shfl_xor(v, 2);  v += __shfl_xor(v, 1); }

// ---------------------------------------------------------------------------
// ONE block per (b, pair); loops over 32 groups. Per-thread: 2 adjacent
// positions as float2 (v_pk_fma_f32, ds_read_b64), register bins, wave
// butterfly reduction. XCD-swizzled blockIdx for L2 locality.
// ---------------------------------------------------------------------------
__global__ void __launch_bounds__(256)
hydra_fused(const float* __restrict__ X, const float* __restrict__ Wt,
            const int* __restrict__ I, float* __restrict__ out)
{
    __shared__ float inp[BUF];
    __shared__ float wavehist[4 * 16];
    const int tid = threadIdx.x;
    // XCD swizzle: blk&7 ~ XCD id (dispatch round-robin heuristic); 16
    // batches per XCD -> per-XCD X working set 1.5 MB < 4 MB L2.
    const int blk  = blockIdx.x;
    const int x    = blk & 7;
    const int r    = blk >> 3;            // [0,256)
    const int b    = x * 16 + (r >> 4);
    const int pair = r & 15;
    const int di    = pair >> 1;
    const int diffi = pair & 1;
    const int D     = 1 << di;
    const int Lout  = CL - diffi;
    const float* __restrict__ Xb = X + (size_t)b * (CC * CL);

    for (int i = tid; i < HALO; i += 256) inp[i] = 0.f;
    for (int i = HALO + CL + tid; i < BUF; i += 256) inp[i] = 0.f;

    #pragma unroll 1
    for (int g = 0; g < CG; ++g) {
        // ---- stage summed (and optionally diffed) row for this group ----
        const int* __restrict__ Ig = I + (pair * CG + g) * CNCP;
        const int ch0 = Ig[0], ch1 = Ig[1], ch2 = Ig[2],
                  ch3 = Ig[3], ch4 = Ig[4], ch5 = Ig[5];
        const float* r0 = Xb + ch0 * CL; const float* r1 = Xb + ch1 * CL;
        const float* r2 = Xb + ch2 * CL; const float* r3 = Xb + ch3 * CL;
        const float* r4 = Xb + ch4 * CL; const float* r5 = Xb + ch5 * CL;

        #pragma unroll
        for (int cc = 0; cc < 2; ++cc) {
            const int pos = cc * 1024 + tid * 4;
            const float4 x0 = ld4(r0 + pos), x1 = ld4(r1 + pos), x2 = ld4(r2 + pos),
                         x3 = ld4(r3 + pos), x4 = ld4(r4 + pos), x5 = ld4(r5 + pos);
            float4 s;
            s.x = ((x0.x + x1.x) + (x2.x + x3.x)) + (x4.x + x5.x);
            s.y = ((x0.y + x1.y) + (x2.y + x3.y)) + (x4.y + x5.y);
            s.z = ((x0.z + x1.z) + (x2.z + x3.z)) + (x4.z + x5.z);
            s.w = ((x0.w + x1.w) + (x2.w + x3.w)) + (x4.w + x5.w);
            if (!diffi) {
                *(float4*)&inp[HALO + pos] = s;
            } else {
                float s4;
                if (pos + 4 < CL)
                    s4 = ((r0[pos + 4] + r1[pos + 4]) + (r2[pos + 4] + r3[pos + 4]))
                         + (r4[pos + 4] + r5[pos + 4]);
                else
                    s4 = s.w; // => diff 0 at padding position 2047
                const float4 d = make_float4(s.y - s.x, s.z - s.y, s.w - s.z, s4 - s.w);
                *(float4*)&inp[HALO + pos] = d;
            }
        }
        __syncthreads();

        // ---- conv + select + register bins, 2 positions/thread (packed) ----
        const float* __restrict__ Wg = Wt + (pair * CG + g) * 72;
        v2f bm0 = {0,0}, bm1 = {0,0}, bm2 = {0,0}, bm3 = {0,0},
            bm4 = {0,0}, bm5 = {0,0}, bm6 = {0,0}, bm7 = {0,0};
        unsigned bnpack = 0; // 8 nibble counters, <=8 each per g per thread

        #pragma unroll 1
        for (int p = 0; p < 4; ++p) {
            const int l = p * 512 + tid * 2;          // even; positions l, l+1
            v2f a0 = {0,0}, a1 = {0,0}, a2 = {0,0}, a3 = {0,0},
                a4 = {0,0}, a5 = {0,0}, a6 = {0,0}, a7 = {0,0};

            #define FK2(J, TV) { const float* wj = Wg + (J) * 8; \
                a0 = __builtin_elementwise_fma((v2f){wj[0], wj[0]}, TV, a0); \
                a1 = __builtin_elementwise_fma((v2f){wj[1], wj[1]}, TV, a1); \
                a2 = __builtin_elementwise_fma((v2f){wj[2], wj[2]}, TV, a2); \
                a3 = __builtin_elementwise_fma((v2f){wj[3], wj[3]}, TV, a3); \
                a4 = __builtin_elementwise_fma((v2f){wj[4], wj[4]}, TV, a4); \
                a5 = __builtin_elementwise_fma((v2f){wj[5], wj[5]}, TV, a5); \
                a6 = __builtin_elementwise_fma((v2f){wj[6], wj[6]}, TV, a6); \
                a7 = __builtin_elementwise_fma((v2f){wj[7], wj[7]}, TV, a7); }

            if (di == 0) {
                // D=1: 10-float window [l-4 .. l+5] in 5 v2f regs (8B aligned)
                const float* base = &inp[HALO + l - 4];
                const v2f W0 = *(const v2f*)(base + 0), W1 = *(const v2f*)(base + 2),
                          W2 = *(const v2f*)(base + 4), W3 = *(const v2f*)(base + 6),
                          W4 = *(const v2f*)(base + 8);
                FK2(0, W0)
                FK2(1, ((v2f){W0.y, W1.x}))
                FK2(2, W1)
                FK2(3, ((v2f){W1.y, W2.x}))
                FK2(4, W2)
                FK2(5, ((v2f){W2.y, W3.x}))
                FK2(6, W3)
                FK2(7, ((v2f){W3.y, W4.x}))
                FK2(8, W4)
            } else {
                // even D: taps at jD + {0,1} -> aligned ds_read_b64 each
                const float* base = &inp[HALO + l - 4 * D];
                #pragma unroll
                for (int j = 0; j < 9; ++j) {
                    const v2f tv = *(const v2f*)(base + j * D);
                    FK2(j, tv)
                }
            }
            #undef FK2

            // packed max/min trees (both positions at once)
            const v2f mx2 = vmax(vmax(vmax(a0, a1), vmax(a2, a3)),
                                 vmax(vmax(a4, a5), vmax(a6, a7)));
            const v2f mn2 = vmin(vmin(vmin(a0, a1), vmin(a2, a3)),
                                 vmin(vmin(a4, a5), vmin(a6, a7)));

            // descending equality scans: final = FIRST k hitting max/min
            int mi0 = 7, mi1 = 7, ni0 = 7, ni1 = 7;
            #define SCANK(K, ak) \
                mi0 = (ak.x == mx2.x) ? (K) : mi0; mi1 = (ak.y == mx2.y) ? (K) : mi1; \
                ni0 = (ak.x == mn2.x) ? (K) : ni0; ni1 = (ak.y == mn2.y) ? (K) : ni1;
            SCANK(6, a6) SCANK(5, a5) SCANK(4, a4) SCANK(3, a3)
            SCANK(2, a2) SCANK(1, a1) SCANK(0, a0)
            #undef SCANK

            // validity: only position 2047 (l+1, p==3, tid==255) invalid when diffi
            const bool v1ok = (l + 1) < Lout;        // l < Lout always (l<=2046)
            if (!v1ok) mi1 = 8;

            #define BINK(K) bm##K += (v2f){ (mi0 == (K)) ? mx2.x : 0.f, \
                                            (mi1 == (K)) ? mx2.y : 0.f };
            BINK(0) BINK(1) BINK(2) BINK(3) BINK(4) BINK(5) BINK(6) BINK(7)
            #undef BINK
            bnpack += (1u << (ni0 * 4)) + (v1ok ? (1u << (ni1 * 4)) : 0u);
        }

        // ---- fold parities, unpack nibbles, wave butterfly reduction ----
        float f0 = bm0.x + bm0.y, f1 = bm1.x + bm1.y, f2 = bm2.x + bm2.y,
              f3 = bm3.x + bm3.y, f4 = bm4.x + bm4.y, f5 = bm5.x + bm5.y,
              f6 = bm6.x + bm6.y, f7 = bm7.x + bm7.y;
        float h0 = (float)((bnpack >>  0) & 15), h1 = (float)((bnpack >>  4) & 15),
              h2 = (float)((bnpack >>  8) & 15), h3 = (float)((bnpack >> 12) & 15),
              h4 = (float)((bnpack >> 16) & 15), h5 = (float)((bnpack >> 20) & 15),
              h6 = (float)((bnpack >> 24) & 15), h7 = (float)((bnpack >> 28) & 15);
        RED64(f0) RED64(f1) RED64(f2) RED64(f3) RED64(f4) RED64(f5) RED64(f6) RED64(f7)
        RED64(h0) RED64(h1) RED64(h2) RED64(h3) RED64(h4) RED64(h5) RED64(h6) RED64(h7)

        if ((tid & 63) == 0) {
            float* wh = wavehist + (tid >> 6) * 16;
            *(float4*)(wh + 0)  = make_float4(f0, f1, f2, f3);
            *(float4*)(wh + 4)  = make_float4(f4, f5, f6, f7);
            *(float4*)(wh + 8)  = make_float4(h0, h1, h2, h3);
            *(float4*)(wh + 12) = make_float4(h4, h5, h6, h7);
        }
        __syncthreads();

        if (tid < 16) {
            const float s = wavehist[tid] + wavehist[16 + tid]
                          + wavehist[32 + tid] + wavehist[48 + tid];
            const int which = tid >> 3, k = tid & 7;
            out[(size_t)b * 8192 + ((pair * 2 + which) * CG + g) * CK + k] = s;
        }
    }
}

extern "C" void kernel_launch(void* const* d_in, const int* in_sizes, int n_in,
                              void* d_out, int out_size, void* d_ws, size_t ws_size,
                              hipStream_t stream)
{
    const float* X = (const float*)d_in[0];
    const float* W = (const float*)d_in[1];
    const int*   I = (const int*)d_in[2];
    float* out = (float*)d_out;
    float* Wt  = (float*)d_ws; // 36864 floats = 144 KiB scratch

    transposeW<<<dim3((36864 + 255) / 256), dim3(256), 0, stream>>>(W, Wt);
    hydra_fused<<<dim3(CB * 16), dim3(256), 0, stream>>>(X, Wt, I, out);
}